// Round 9
// baseline (342.286 us; speedup 1.0000x reference)
//
#include <hip/hip_runtime.h>
#include <hip/hip_bf16.h>

#define Dd 64
#define Hh 128
#define Ww 128
#define Cc 32

// block tile: 32d x 16h x 16w outputs; wave = 8d x 16h x 16w
#define BD 32
#define BH 16
#define BW 16
#define ZR (BD + 6)        // 38 staged z-planes
#define HR (BH + 6)        // 22 staged h-rows
#define NR (ZR * HR)       // 836 (z,h) rows
#define RCOLS 24           // bf16 cols per row; col = w - w0 + 4 (left halo 4)
#define BLKROW 3
#define NBLK (NR * BLKROW) // 2508 16B blocks to stage

#define NPL 58             // 49 (7^3 kd*7+kh) + 9 (3^3 kd3*3+kh3) planes
#define NWIN 15            // A-windows: astart 9..22 real (14) + 1 zero window

typedef __attribute__((ext_vector_type(8))) short short8;   // 8 bf16 (4 VGPR)
typedef __attribute__((ext_vector_type(4))) float floatx4;  // MFMA acc

static __device__ __forceinline__ unsigned short f2bf(float f) {
    unsigned u = __builtin_bit_cast(unsigned, f);
    u += 0x7fffu + ((u >> 16) & 1u);   // RNE
    return (unsigned short)(u >> 16);
}

static __device__ __forceinline__ unsigned pk2(float a, float b) {
    union { __hip_bfloat162 h; unsigned u; } cv;
    cv.h = __float22bfloat162_rn(make_float2(a, b));   // v_cvt_pk_bf16_f32
    return cv.u;
}

__global__ __launch_bounds__(256, 3) void replk_mfma(
    const float* __restrict__ x,
    const float* __restrict__ w7, const float* __restrict__ w3, const float* __restrict__ w1,
    const float* __restrict__ g7, const float* __restrict__ b7, const float* __restrict__ m7, const float* __restrict__ v7,
    const float* __restrict__ g3, const float* __restrict__ b3, const float* __restrict__ m3, const float* __restrict__ v3,
    const float* __restrict__ g1, const float* __restrict__ b1, const float* __restrict__ m1, const float* __restrict__ v1,
    float* __restrict__ out)
{
    __shared__ __align__(16) unsigned short tile[NR * RCOLS];    // 39.2 KB; 48B pitch
    __shared__ __align__(16) unsigned short wtab[NPL * NWIN * 8]; // 13.6 KB A-frag table

    const int tid = threadIdx.x;

    // XCD-aware swizzle: 8192 blocks, 8 XCDs, 1024 contiguous per XCD
    // => all 128 tiles of a (n,c) slab land on one XCD (halo L2 reuse).
    const unsigned lid = blockIdx.x;
    const unsigned nl = (lid & 7u) * 1024u + (lid >> 3);
    const int bx = nl & 127;
    const int slab = nl >> 7;
    const int c = slab & 31;
    const int nb = slab >> 5;
    const int w0 = (bx & 7) * BW;
    const int h0 = ((bx >> 3) & 7) * BH;
    const int d0 = (bx >> 6) * BD;

    const float* xc = x + (size_t)(nb * Cc + c) * (Dd * Hh * Ww);

    // ---- build A-fragment table: one 16B entry per (plane, window) ----
    // entry (pl, aidx) = Wpad[9+aidx .. 9+aidx+8) of that plane's band,
    // where Wpad7[i]=wt7[i-16] (i-16 in [0,7)), Wpad3[i]=wt3[i-18] ([0,3)).
    // => elem j: t7 = aidx+j-7 (valid [0,7)), t3 = aidx+j-9 (valid [0,3)).
    // aidx=14 (astart>=23 or <=8 lanes) is all-zero by construction.
    for (int e = tid; e < NPL * NWIN; e += 256) {
        int pl = e / NWIN, aidx = e - pl * NWIN;
        unsigned short h8[8];
#pragma unroll
        for (int j = 0; j < 8; j++) {
            float v = 0.f;
            if (pl < 49) {
                int t = aidx + j - 7;
                if ((unsigned)t < 7u)
                    v = w7[c * 343 + (pl / 7) * 49 + (pl % 7) * 7 + t];
            } else {
                int p3 = pl - 49;
                int t = aidx + j - 9;
                if ((unsigned)t < 3u)
                    v = w3[c * 27 + (p3 / 3) * 9 + (p3 % 3) * 3 + t];
            }
            h8[j] = f2bf(v);
        }
        uint4 pk;
        pk.x = (unsigned)h8[0] | ((unsigned)h8[1] << 16);
        pk.y = (unsigned)h8[2] | ((unsigned)h8[3] << 16);
        pk.z = (unsigned)h8[4] | ((unsigned)h8[5] << 16);
        pk.w = (unsigned)h8[6] | ((unsigned)h8[7] << 16);
        *(uint4*)&wtab[e * 8] = pk;
    }

    // ---- stage input tile fp32 -> bf16 (cvt_pk), 24 cols/row, left halo 4 ----
#pragma unroll
    for (int it = 0; it < 10; it++) {
        int s = tid + it * 256;
        if (s < NBLK) {
            int R = s / BLKROW, bl = s - R * BLKROW;
            int zi = R / HR, hr = R - zi * HR;
            int gz = d0 - 3 + zi, gh = h0 - 3 + hr, gw0 = w0 - 4 + bl * 8;
            float v[8];
#pragma unroll
            for (int j = 0; j < 8; j++) v[j] = 0.f;
            if ((unsigned)gz < (unsigned)Dd && (unsigned)gh < (unsigned)Hh) {
                const float* src = xc + ((size_t)gz * Hh + gh) * Ww + gw0;
                if (gw0 >= 0 && gw0 + 8 <= Ww) {
                    float4 a = *(const float4*)src;
                    float4 b = *(const float4*)(src + 4);
                    v[0] = a.x; v[1] = a.y; v[2] = a.z; v[3] = a.w;
                    v[4] = b.x; v[5] = b.y; v[6] = b.z; v[7] = b.w;
                } else {
#pragma unroll
                    for (int j = 0; j < 8; j++) {
                        int gw = gw0 + j;
                        if ((unsigned)gw < (unsigned)Ww) v[j] = src[j];
                    }
                }
            }
            uint4 pk;
            pk.x = pk2(v[0], v[1]);
            pk.y = pk2(v[2], v[3]);
            pk.z = pk2(v[4], v[5]);
            pk.w = pk2(v[6], v[7]);
            *(uint4*)&tile[R * RCOLS + bl * 8] = pk;
        }
    }

    // BN constants (wave-uniform)
    const float eps = 1e-5f;
    const float iv7 = g7[c] / sqrtf(v7[c] + eps);
    const float bb7 = b7[c] - m7[c] * iv7;
    const float iv3 = g3[c] / sqrtf(v3[c] + eps);
    const float bb3 = b3[c] - m3[c] * iv3;
    const float iv1 = g1[c] / sqrtf(v1[c] + eps);
    const float bb1 = b1[c] - m1[c] * iv1;
    const float s1 = w1[c] * iv1;

    __syncthreads();

    const int lane = tid & 63;
    const int wave = tid >> 6;
    const int q = lane & 15;          // n (h-row) for B; m for A
    const int p = lane >> 4;          // k-group
    const int cg = (p == 3) ? 0 : p;  // p=3's A is all-zero; broadcast-alias B read
    const int zbase = wave * 8;       // wave owns d-outputs [zbase, zbase+8)

    // A-window index: astart = 8p-q+15; real windows astart in [9,23), else zero
    const int astart = 8 * p - q + 15;
    const int aidx = ((unsigned)(astart - 9) < 14u) ? (astart - 9) : 14;
    const short8* wf = (const short8*)wtab;

    floatx4 acc7[8], acc3[8];
#pragma unroll
    for (int i = 0; i < 8; i++) { acc7[i] = (floatx4)0.f; acc3[i] = (floatx4)0.f; }

    // ---- kh-outer main loop: 10 A-frags live (1 b128 each), B row per zi ----
#pragma unroll 1
    for (int kh = 0; kh < 7; kh++) {
        short8 A7k[7];
#pragma unroll
        for (int kd = 0; kd < 7; kd++)
            A7k[kd] = wf[(kd * 7 + kh) * NWIN + aidx];

        const bool has3 = (kh >= 2) && (kh < 5);
        short8 A3k[3] = {};
        if (has3) {
            const int kh3 = kh - 2;
#pragma unroll
            for (int kd3 = 0; kd3 < 3; kd3++)
                A3k[kd3] = wf[(49 + kd3 * 3 + kh3) * NWIN + aidx];
        }

#pragma unroll
        for (int zi = 0; zi < 14; zi++) {
            const int R = (zbase + zi) * HR + q + kh;
            short8 B = *(const short8*)&tile[R * RCOLS + cg * 8];
            __builtin_amdgcn_s_setprio(1);
#pragma unroll
            for (int kd = 6; kd >= 0; kd--) {
                const int dd = zi - kd;
                if (dd >= 0 && dd < 8)
                    acc7[dd] = __builtin_amdgcn_mfma_f32_16x16x32_bf16(
                        A7k[kd], B, acc7[dd], 0, 0, 0);
            }
            if (has3) {
#pragma unroll
                for (int kd3 = 2; kd3 >= 0; kd3--) {
                    const int dd = zi - 2 - kd3;
                    if (dd >= 0 && dd < 8)
                        acc3[dd] = __builtin_amdgcn_mfma_f32_16x16x32_bf16(
                            A3k[kd3], B, acc3[dd], 0, 0, 0);
                }
            }
            __builtin_amdgcn_s_setprio(0);
        }
    }

    // ---- epilogue: residual x read from LDS tile (bf16), no global re-read ----
    // C/D layout: col(n=h)=lane&15, row(m=w)=(lane>>4)*4+reg; center col = m+4
#pragma unroll
    for (int dd = 0; dd < 8; dd++) {
        int d = d0 + zbase + dd;
        const int R = (zbase + dd + 3) * HR + (q + 3);
        uint2 u = *(const uint2*)&tile[R * RCOLS + 4 * p + 4];   // 8B-aligned
        float xr[4];
        xr[0] = __builtin_bit_cast(float, u.x << 16);
        xr[1] = __builtin_bit_cast(float, u.x & 0xffff0000u);
        xr[2] = __builtin_bit_cast(float, u.y << 16);
        xr[3] = __builtin_bit_cast(float, u.y & 0xffff0000u);

        size_t off = ((size_t)(nb * Cc + c) * Dd + d) * (Hh * Ww)
                   + (size_t)(h0 + q) * Ww + w0 + p * 4;
        float o[4];
#pragma unroll
        for (int r = 0; r < 4; r++) {
            float y7 = fmaxf(fmaf(acc7[dd][r], iv7, bb7), 0.f);
            float y3 = fmaxf(fmaf(acc3[dd][r], iv3, bb3), 0.f);
            float y1 = fmaxf(fmaf(xr[r], s1, bb1), 0.f);
            o[r] = fmaxf(xr[r] + y7 + y3 + y1, 0.f);
        }
        *(float4*)(out + off) = make_float4(o[0], o[1], o[2], o[3]);
    }
}

extern "C" void kernel_launch(void* const* d_in, const int* in_sizes, int n_in,
                              void* d_out, int out_size, void* d_ws, size_t ws_size,
                              hipStream_t stream) {
    const float* x  = (const float*)d_in[0];
    const float* w7 = (const float*)d_in[1];
    const float* w3 = (const float*)d_in[2];
    const float* w1 = (const float*)d_in[3];
    const float* g7 = (const float*)d_in[4];
    const float* b7 = (const float*)d_in[5];
    const float* m7 = (const float*)d_in[6];
    const float* v7 = (const float*)d_in[7];
    const float* g3 = (const float*)d_in[8];
    const float* b3 = (const float*)d_in[9];
    const float* m3 = (const float*)d_in[10];
    const float* v3 = (const float*)d_in[11];
    const float* g1 = (const float*)d_in[12];
    const float* b1 = (const float*)d_in[13];
    const float* m1 = (const float*)d_in[14];
    const float* v1 = (const float*)d_in[15];
    float* out = (float*)d_out;

    dim3 grid(8192);   // 1-D; kernel swizzles to (slab, tile) XCD-contiguously
    dim3 block(256);
    hipLaunchKernelGGL(replk_mfma, grid, block, 0, stream,
                       x, w7, w3, w1, g7, b7, m7, v7, g3, b3, m3, v3,
                       g1, b1, m1, v1, out);
}

// Round 10
// 279.814 us; speedup vs baseline: 1.2233x; 1.2233x over previous
//
#include <hip/hip_runtime.h>
#include <hip/hip_bf16.h>

#define Dd 64
#define Hh 128
#define Ww 128
#define Cc 32

// block tile: 32d x 16h x 16w outputs; wave = 8d x 16h x 16w
#define BD 32
#define BH 16
#define BW 16
#define ZR (BD + 6)        // 38 staged z-planes
#define HR (BH + 6)        // 22 staged h-rows
#define NR (ZR * HR)       // 836 (z,h) rows
#define RCOLS 24           // bf16 cols per row; col = w - w0 + 4 (left halo 4)
#define BLKROW 3
#define NBLK (NR * BLKROW) // 2508 16B blocks to stage

// A-fragment table: 49 7^3-planes x 14 windows + 9 3^3-planes x 10 windows
// + 1 shared all-zero entry. 777 entries x 16B = 12432 B.
#define N7WIN 14
#define N3WIN 10
#define W3BASE (49 * N7WIN)          // 686
#define ZENT   (W3BASE + 9 * N3WIN) // 776
#define NENT   (ZENT + 1)           // 777

typedef __attribute__((ext_vector_type(8))) short short8;   // 8 bf16 (4 VGPR)
typedef __attribute__((ext_vector_type(4))) float floatx4;  // MFMA acc

static __device__ __forceinline__ unsigned short f2bf(float f) {
    unsigned u = __builtin_bit_cast(unsigned, f);
    u += 0x7fffu + ((u >> 16) & 1u);   // RNE
    return (unsigned short)(u >> 16);
}

static __device__ __forceinline__ unsigned pk2(float a, float b) {
    union { __hip_bfloat162 h; unsigned u; } cv;
    cv.h = __float22bfloat162_rn(make_float2(a, b));   // v_cvt_pk_bf16_f32
    return cv.u;
}

__global__ __launch_bounds__(256, 3) void replk_mfma(
    const float* __restrict__ x,
    const float* __restrict__ w7, const float* __restrict__ w3, const float* __restrict__ w1,
    const float* __restrict__ g7, const float* __restrict__ b7, const float* __restrict__ m7, const float* __restrict__ v7,
    const float* __restrict__ g3, const float* __restrict__ b3, const float* __restrict__ m3, const float* __restrict__ v3,
    const float* __restrict__ g1, const float* __restrict__ b1, const float* __restrict__ m1, const float* __restrict__ v1,
    float* __restrict__ out)
{
    __shared__ __align__(16) unsigned short tile[NR * RCOLS];  // 40128 B; 48B pitch
    __shared__ __align__(16) unsigned short wtab[NENT * 8];    // 12432 B
    // total 52560 B raw -> 2048-granule alloc 53248; x3 = 159744 <= 160 KiB -> 3 blocks/CU

    const int tid = threadIdx.x;

    // XCD-aware swizzle: 8192 blocks, 8 XCDs, 1024 contiguous per XCD
    // => all 128 tiles of a (n,c) slab land on one XCD (halo L2 reuse).
    const unsigned lid = blockIdx.x;
    const unsigned nl = (lid & 7u) * 1024u + (lid >> 3);
    const int bx = nl & 127;
    const int slab = nl >> 7;
    const int c = slab & 31;
    const int nb = slab >> 5;
    const int w0 = (bx & 7) * BW;
    const int h0 = ((bx >> 3) & 7) * BH;
    const int d0 = (bx >> 6) * BD;

    const float* xc = x + (size_t)(nb * Cc + c) * (Dd * Hh * Ww);

    // ---- build A-fragment table ----
    // 7^3 entry (pl, a7): elem j = (t = a7+j-7 in [0,7)) ? wt7[kd][kh][t] : 0
    // 3^3 entry (p3, a3): elem j = (t = a3+j-7 in [0,3)) ? wt3[kd3][kh3][t] : 0
    // entry ZENT: zeros (all invalid-window lanes broadcast-read this one).
    for (int e = tid; e < NENT; e += 256) {
        unsigned short h8[8];
#pragma unroll
        for (int j = 0; j < 8; j++) {
            float v = 0.f;
            if (e < W3BASE) {
                int pl = e / N7WIN, a = e - pl * N7WIN;
                int t = a + j - 7;
                if ((unsigned)t < 7u)
                    v = w7[c * 343 + (pl / 7) * 49 + (pl % 7) * 7 + t];
            } else if (e < ZENT) {
                int e2 = e - W3BASE;
                int p3 = e2 / N3WIN, a = e2 - p3 * N3WIN;
                int t = a + j - 7;
                if ((unsigned)t < 3u)
                    v = w3[c * 27 + (p3 / 3) * 9 + (p3 % 3) * 3 + t];
            }
            h8[j] = f2bf(v);
        }
        uint4 pk;
        pk.x = (unsigned)h8[0] | ((unsigned)h8[1] << 16);
        pk.y = (unsigned)h8[2] | ((unsigned)h8[3] << 16);
        pk.z = (unsigned)h8[4] | ((unsigned)h8[5] << 16);
        pk.w = (unsigned)h8[6] | ((unsigned)h8[7] << 16);
        *(uint4*)&wtab[e * 8] = pk;
    }

    // ---- stage input tile fp32 -> bf16 (cvt_pk), 24 cols/row, left halo 4 ----
#pragma unroll
    for (int it = 0; it < 10; it++) {
        int s = tid + it * 256;
        if (s < NBLK) {
            int R = s / BLKROW, bl = s - R * BLKROW;
            int zi = R / HR, hr = R - zi * HR;
            int gz = d0 - 3 + zi, gh = h0 - 3 + hr, gw0 = w0 - 4 + bl * 8;
            float v[8];
#pragma unroll
            for (int j = 0; j < 8; j++) v[j] = 0.f;
            if ((unsigned)gz < (unsigned)Dd && (unsigned)gh < (unsigned)Hh) {
                const float* src = xc + ((size_t)gz * Hh + gh) * Ww + gw0;
                if (gw0 >= 0 && gw0 + 8 <= Ww) {
                    float4 a = *(const float4*)src;
                    float4 b = *(const float4*)(src + 4);
                    v[0] = a.x; v[1] = a.y; v[2] = a.z; v[3] = a.w;
                    v[4] = b.x; v[5] = b.y; v[6] = b.z; v[7] = b.w;
                } else {
#pragma unroll
                    for (int j = 0; j < 8; j++) {
                        int gw = gw0 + j;
                        if ((unsigned)gw < (unsigned)Ww) v[j] = src[j];
                    }
                }
            }
            uint4 pk;
            pk.x = pk2(v[0], v[1]);
            pk.y = pk2(v[2], v[3]);
            pk.z = pk2(v[4], v[5]);
            pk.w = pk2(v[6], v[7]);
            *(uint4*)&tile[R * RCOLS + bl * 8] = pk;
        }
    }

    // BN constants (wave-uniform)
    const float eps = 1e-5f;
    const float iv7 = g7[c] / sqrtf(v7[c] + eps);
    const float bb7 = b7[c] - m7[c] * iv7;
    const float iv3 = g3[c] / sqrtf(v3[c] + eps);
    const float bb3 = b3[c] - m3[c] * iv3;
    const float iv1 = g1[c] / sqrtf(v1[c] + eps);
    const float bb1 = b1[c] - m1[c] * iv1;
    const float s1 = w1[c] * iv1;

    __syncthreads();

    const int lane = tid & 63;
    const int wave = tid >> 6;
    const int q = lane & 15;          // n (h-row) for B; m for A
    const int p = lane >> 4;          // k-group
    const int cg = (p == 3) ? 0 : p;  // p=3's A is all-zero; broadcast-alias B read
    const int zbase = wave * 8;       // wave owns d-outputs [zbase, zbase+8)

    // A-window select: astart = 8p-q+15
    //   7^3 real windows: astart in [9,23)  -> a7 = astart-9  in [0,14)
    //   3^3 real windows: astart in [11,21) -> a3 = astart-11 in [0,10)
    // invalid -> shared zero entry (ZENT). idx = pl*mul + off (mul/off lane-const).
    const int astart = 8 * p - q + 15;
    const bool ok7 = (unsigned)(astart - 9) < (unsigned)N7WIN;
    const bool ok3 = (unsigned)(astart - 11) < (unsigned)N3WIN;
    const int mul7 = ok7 ? N7WIN : 0;
    const int off7 = ok7 ? (astart - 9) : ZENT;
    const int mul3 = ok3 ? N3WIN : 0;
    const int off3 = ok3 ? (W3BASE + astart - 11) : ZENT;
    const short8* wf = (const short8*)wtab;

    floatx4 acc7[8], acc3[8];
#pragma unroll
    for (int i = 0; i < 8; i++) { acc7[i] = (floatx4)0.f; acc3[i] = (floatx4)0.f; }

    // ---- kh-outer main loop: 10 A-frags live (1 b128 each), B row per zi ----
#pragma unroll 1
    for (int kh = 0; kh < 7; kh++) {
        short8 A7k[7];
#pragma unroll
        for (int kd = 0; kd < 7; kd++)
            A7k[kd] = wf[(kd * 7 + kh) * mul7 + off7];

        const bool has3 = (kh >= 2) && (kh < 5);
        short8 A3k[3] = {};
        if (has3) {
            const int kh3 = kh - 2;
#pragma unroll
            for (int kd3 = 0; kd3 < 3; kd3++)
                A3k[kd3] = wf[(kd3 * 3 + kh3) * mul3 + off3];
        }

#pragma unroll
        for (int zi = 0; zi < 14; zi++) {
            const int R = (zbase + zi) * HR + q + kh;
            short8 B = *(const short8*)&tile[R * RCOLS + cg * 8];
            __builtin_amdgcn_s_setprio(1);
#pragma unroll
            for (int kd = 6; kd >= 0; kd--) {
                const int dd = zi - kd;
                if (dd >= 0 && dd < 8)
                    acc7[dd] = __builtin_amdgcn_mfma_f32_16x16x32_bf16(
                        A7k[kd], B, acc7[dd], 0, 0, 0);
            }
            if (has3) {
#pragma unroll
                for (int kd3 = 2; kd3 >= 0; kd3--) {
                    const int dd = zi - 2 - kd3;
                    if (dd >= 0 && dd < 8)
                        acc3[dd] = __builtin_amdgcn_mfma_f32_16x16x32_bf16(
                            A3k[kd3], B, acc3[dd], 0, 0, 0);
                }
            }
            __builtin_amdgcn_s_setprio(0);
        }
    }

    // ---- epilogue: residual x read from LDS tile (bf16), no global re-read ----
    // C/D layout: col(n=h)=lane&15, row(m=w)=(lane>>4)*4+reg; center col = m+4
#pragma unroll
    for (int dd = 0; dd < 8; dd++) {
        int d = d0 + zbase + dd;
        const int R = (zbase + dd + 3) * HR + (q + 3);
        uint2 u = *(const uint2*)&tile[R * RCOLS + 4 * p + 4];   // 8B-aligned
        float xr[4];
        xr[0] = __builtin_bit_cast(float, u.x << 16);
        xr[1] = __builtin_bit_cast(float, u.x & 0xffff0000u);
        xr[2] = __builtin_bit_cast(float, u.y << 16);
        xr[3] = __builtin_bit_cast(float, u.y & 0xffff0000u);

        size_t off = ((size_t)(nb * Cc + c) * Dd + d) * (Hh * Ww)
                   + (size_t)(h0 + q) * Ww + w0 + p * 4;
        float o[4];
#pragma unroll
        for (int r = 0; r < 4; r++) {
            float y7 = fmaxf(fmaf(acc7[dd][r], iv7, bb7), 0.f);
            float y3 = fmaxf(fmaf(acc3[dd][r], iv3, bb3), 0.f);
            float y1 = fmaxf(fmaf(xr[r], s1, bb1), 0.f);
            o[r] = fmaxf(xr[r] + y7 + y3 + y1, 0.f);
        }
        *(float4*)(out + off) = make_float4(o[0], o[1], o[2], o[3]);
    }
}

extern "C" void kernel_launch(void* const* d_in, const int* in_sizes, int n_in,
                              void* d_out, int out_size, void* d_ws, size_t ws_size,
                              hipStream_t stream) {
    const float* x  = (const float*)d_in[0];
    const float* w7 = (const float*)d_in[1];
    const float* w3 = (const float*)d_in[2];
    const float* w1 = (const float*)d_in[3];
    const float* g7 = (const float*)d_in[4];
    const float* b7 = (const float*)d_in[5];
    const float* m7 = (const float*)d_in[6];
    const float* v7 = (const float*)d_in[7];
    const float* g3 = (const float*)d_in[8];
    const float* b3 = (const float*)d_in[9];
    const float* m3 = (const float*)d_in[10];
    const float* v3 = (const float*)d_in[11];
    const float* g1 = (const float*)d_in[12];
    const float* b1 = (const float*)d_in[13];
    const float* m1 = (const float*)d_in[14];
    const float* v1 = (const float*)d_in[15];
    float* out = (float*)d_out;

    dim3 grid(8192);   // 1-D; kernel swizzles to (slab, tile) XCD-contiguously
    dim3 block(256);
    hipLaunchKernelGGL(replk_mfma, grid, block, 0, stream,
                       x, w7, w3, w1, g7, b7, m7, v7, g3, b3, m3, v3,
                       g1, b1, m1, v1, out);
}

// Round 11
// 262.118 us; speedup vs baseline: 1.3058x; 1.0675x over previous
//
#include <hip/hip_runtime.h>
#include <hip/hip_bf16.h>

#define Dd 64
#define Hh 128
#define Ww 128
#define Cc 32

// block tile: 32d x 16h x 16w outputs; wave = 8d x 16h x 16w
#define BD 32
#define BH 16
#define BW 16
#define ZR (BD + 6)        // 38 staged z-planes
#define HR (BH + 6)        // 22 staged h-rows
#define NR (ZR * HR)       // 836 (z,h) rows
#define RCOLS 24           // bf16 cols per row; col = w - w0 + 4 (left halo 4)
#define BLKROW 3
#define NBLK (NR * BLKROW) // 2508 16B blocks to stage

// A-fragment table (identical to r10): 49 7^3-planes x 14 windows +
// 9 3^3-planes x 10 windows + 1 shared all-zero entry.
#define N7WIN 14
#define N3WIN 10
#define W3BASE (49 * N7WIN)          // 686
#define ZENT   (W3BASE + 9 * N3WIN) // 776
#define NENT   (ZENT + 1)           // 777

typedef __attribute__((ext_vector_type(8))) short short8;   // 8 bf16 (4 VGPR)
typedef __attribute__((ext_vector_type(4))) float floatx4;  // MFMA acc

static __device__ __forceinline__ unsigned short f2bf(float f) {
    unsigned u = __builtin_bit_cast(unsigned, f);
    u += 0x7fffu + ((u >> 16) & 1u);   // RNE
    return (unsigned short)(u >> 16);
}

static __device__ __forceinline__ unsigned pk2(float a, float b) {
    union { __hip_bfloat162 h; unsigned u; } cv;
    cv.h = __float22bfloat162_rn(make_float2(a, b));   // v_cvt_pk_bf16_f32
    return cv.u;
}

// Scheme-2 MFMA mapping (16x16x32):
//   M = m = (ddl, mw): ddl = m>>3 (2 d's), mw = m&7 (8 w's)
//   K = k = (khp, wc): khp = k>>4 (2 kh's), wc = k&15 (16 staged cols)
//   N = n = h-row (16)
// Per-lane: A/B m|n = lane&15 = q, k = (lane>>4)*8 + j -> khp = p>>1, wc = 8(p&1)+j.
__global__ __launch_bounds__(256, 3) void replk_mfma(
    const float* __restrict__ x,
    const float* __restrict__ w7, const float* __restrict__ w3, const float* __restrict__ w1,
    const float* __restrict__ g7, const float* __restrict__ b7, const float* __restrict__ m7, const float* __restrict__ v7,
    const float* __restrict__ g3, const float* __restrict__ b3, const float* __restrict__ m3, const float* __restrict__ v3,
    const float* __restrict__ g1, const float* __restrict__ b1, const float* __restrict__ m1, const float* __restrict__ v1,
    float* __restrict__ out)
{
    __shared__ __align__(16) unsigned short tile[NR * RCOLS];  // 40128 B; 48B pitch
    __shared__ __align__(16) unsigned short wtab[NENT * 8];    // 12432 B
    // total 52560 raw -> 53248 granule; x3 = 159744 <= 160 KiB -> 3 blocks/CU

    const int tid = threadIdx.x;

    // XCD-aware swizzle: 8192 blocks, 8 XCDs, 1024 contiguous per XCD.
    const unsigned lid = blockIdx.x;
    const unsigned nl = (lid & 7u) * 1024u + (lid >> 3);
    const int bx = nl & 127;
    const int slab = nl >> 7;
    const int c = slab & 31;
    const int nb = slab >> 5;
    const int w0 = (bx & 7) * BW;
    const int h0 = ((bx >> 3) & 7) * BH;
    const int d0 = (bx >> 6) * BD;

    const float* xc = x + (size_t)(nb * Cc + c) * (Dd * Hh * Ww);

    // ---- build A-fragment table (unchanged from r10) ----
    for (int e = tid; e < NENT; e += 256) {
        unsigned short h8[8];
#pragma unroll
        for (int j = 0; j < 8; j++) {
            float v = 0.f;
            if (e < W3BASE) {
                int pl = e / N7WIN, a = e - pl * N7WIN;
                int t = a + j - 7;
                if ((unsigned)t < 7u)
                    v = w7[c * 343 + (pl / 7) * 49 + (pl % 7) * 7 + t];
            } else if (e < ZENT) {
                int e2 = e - W3BASE;
                int p3 = e2 / N3WIN, a = e2 - p3 * N3WIN;
                int t = a + j - 7;
                if ((unsigned)t < 3u)
                    v = w3[c * 27 + (p3 / 3) * 9 + (p3 % 3) * 3 + t];
            }
            h8[j] = f2bf(v);
        }
        uint4 pk;
        pk.x = (unsigned)h8[0] | ((unsigned)h8[1] << 16);
        pk.y = (unsigned)h8[2] | ((unsigned)h8[3] << 16);
        pk.z = (unsigned)h8[4] | ((unsigned)h8[5] << 16);
        pk.w = (unsigned)h8[6] | ((unsigned)h8[7] << 16);
        *(uint4*)&wtab[e * 8] = pk;
    }

    // ---- stage input tile fp32 -> bf16 (cvt_pk), 24 cols/row, left halo 4 ----
#pragma unroll
    for (int it = 0; it < 10; it++) {
        int s = tid + it * 256;
        if (s < NBLK) {
            int R = s / BLKROW, bl = s - R * BLKROW;
            int zi = R / HR, hr = R - zi * HR;
            int gz = d0 - 3 + zi, gh = h0 - 3 + hr, gw0 = w0 - 4 + bl * 8;
            float v[8];
#pragma unroll
            for (int j = 0; j < 8; j++) v[j] = 0.f;
            if ((unsigned)gz < (unsigned)Dd && (unsigned)gh < (unsigned)Hh) {
                const float* src = xc + ((size_t)gz * Hh + gh) * Ww + gw0;
                if (gw0 >= 0 && gw0 + 8 <= Ww) {
                    float4 a = *(const float4*)src;
                    float4 b = *(const float4*)(src + 4);
                    v[0] = a.x; v[1] = a.y; v[2] = a.z; v[3] = a.w;
                    v[4] = b.x; v[5] = b.y; v[6] = b.z; v[7] = b.w;
                } else {
#pragma unroll
                    for (int j = 0; j < 8; j++) {
                        int gw = gw0 + j;
                        if ((unsigned)gw < (unsigned)Ww) v[j] = src[j];
                    }
                }
            }
            uint4 pk;
            pk.x = pk2(v[0], v[1]);
            pk.y = pk2(v[2], v[3]);
            pk.z = pk2(v[4], v[5]);
            pk.w = pk2(v[6], v[7]);
            *(uint4*)&tile[R * RCOLS + bl * 8] = pk;
        }
    }

    // BN constants (wave-uniform)
    const float eps = 1e-5f;
    const float iv7 = g7[c] / sqrtf(v7[c] + eps);
    const float bb7 = b7[c] - m7[c] * iv7;
    const float iv3 = g3[c] / sqrtf(v3[c] + eps);
    const float bb3 = b3[c] - m3[c] * iv3;
    const float iv1 = g1[c] / sqrtf(v1[c] + eps);
    const float bb1 = b1[c] - m1[c] * iv1;
    const float s1 = w1[c] * iv1;

    __syncthreads();

    const int lane = tid & 63;
    const int wave = tid >> 6;
    const int q = lane & 15;          // m (A) / n (B,C,D)
    const int p = lane >> 4;
    const int khp = p >> 1;           // kh within pair
    const int kb  = p & 1;            // wc 16B-block
    const int ddl = q >> 3;           // d within M-pair (A side)
    const int mwq = q & 7;            // w within M (A side)
    const int zbase = wave * 8;       // wave owns d-outputs [zbase, zbase+8)

    // A windows: elem j of entry a gives tap t = a + j - 7.
    // need t7 = wc - mw - 1 -> a7 = 8*kb - mwq + 6 (in [-1,14], valid [0,14))
    // need t3 = wc - mw - 3 -> a3 = a7 - 2          (valid [0,10))
    const int a7 = 8 * kb - mwq + 6;
    const int a3 = a7 - 2;
    const short8* wf = (const short8*)wtab;

    floatx4 acc7[4][2], acc3[4][2];
#pragma unroll
    for (int i = 0; i < 4; i++)
#pragma unroll
        for (int wh = 0; wh < 2; wh++) { acc7[i][wh] = (floatx4)0.f; acc3[i][wh] = (floatx4)0.f; }

    // ---- khg-outer loop: kh-pairs {0,1}{2,3}{4,5}{6,-}; 3^3 shares B of khg 1,2 ----
#pragma unroll 1
    for (int khg = 0; khg < 4; khg++) {
        const int kh = 2 * khg + khp;                       // 0..7 (7 = zero)
        const bool ok7 = ((unsigned)a7 < 14u) && (kh <= 6);
        // idx(rz) = ((rz-ddl)*7 + kh)*14 + a7 = rz*98 + (kh*14 + a7 - ddl*98)
        const int cb7 = ok7 ? (kh * 14 + a7 - ddl * 98) : (int)ZENT;
        const int st7 = ok7 ? 98 : 0;
        short8 A7g[8];
#pragma unroll
        for (int rz = 0; rz < 8; rz++) {
            int idx = cb7 + rz * st7;
            if (rz == 0) idx = (ddl == 0 && ok7) ? idx : (int)ZENT;  // kd=-1 lanes
            if (rz == 7) idx = (ddl == 1 && ok7) ? idx : (int)ZENT;  // kd=7 lanes
            A7g[rz] = wf[idx];
        }

        const bool has3 = (khg == 1) || (khg == 2);
        short8 A3g[4] = {};
        if (has3) {
            const int kh3 = 2 * (khg - 1) + khp;            // 0..3 (3 = zero)
            const bool ok3 = ((unsigned)a3 < 10u) && (kh3 <= 2);
            const int cb3 = ok3 ? (W3BASE + kh3 * 10 + a3 - ddl * 30) : (int)ZENT;
            const int st3 = ok3 ? 30 : 0;
#pragma unroll
            for (int rz = 0; rz < 4; rz++) {
                int idx = cb3 + rz * st3;
                if (rz == 0) idx = (ddl == 0 && ok3) ? idx : (int)ZENT;
                if (rz == 3) idx = (ddl == 1 && ok3) ? idx : (int)ZENT;
                A3g[rz] = wf[idx];
            }
        }

        // kh=7 lanes (khg=3, khp=1) have zero A: clamp their B row to kh=6's (in-range).
        const int rowadd = (khg == 3) ? 6 : (2 * khg + khp);

#pragma unroll
        for (int zi = 0; zi < 14; zi++) {
            const int R = (zbase + zi) * HR + q + rowadd;
            const unsigned short* bp = &tile[R * RCOLS + 8 * kb];
            short8 B0 = *(const short8*)bp;          // wh=0: cols [8kb, 8kb+16)
            short8 B1 = *(const short8*)(bp + 8);    // wh=1: cols [8kb+8, ...)
            __builtin_amdgcn_s_setprio(1);
#pragma unroll
            for (int ddg = 0; ddg < 4; ddg++) {
                const int rz = zi - 2 * ddg;
                if (rz >= 0 && rz < 8) {
                    acc7[ddg][0] = __builtin_amdgcn_mfma_f32_16x16x32_bf16(
                        A7g[rz], B0, acc7[ddg][0], 0, 0, 0);
                    acc7[ddg][1] = __builtin_amdgcn_mfma_f32_16x16x32_bf16(
                        A7g[rz], B1, acc7[ddg][1], 0, 0, 0);
                }
            }
            if (has3) {
#pragma unroll
                for (int ddg = 0; ddg < 4; ddg++) {
                    const int rz3 = zi - 2 - 2 * ddg;
                    if (rz3 >= 0 && rz3 < 4) {
                        acc3[ddg][0] = __builtin_amdgcn_mfma_f32_16x16x32_bf16(
                            A3g[rz3], B0, acc3[ddg][0], 0, 0, 0);
                        acc3[ddg][1] = __builtin_amdgcn_mfma_f32_16x16x32_bf16(
                            A3g[rz3], B1, acc3[ddg][1], 0, 0, 0);
                    }
                }
            }
            __builtin_amdgcn_s_setprio(0);
        }
    }

    // ---- epilogue: C/D col n=lane&15=q (h), row m=4p+r -> ddl=p>>1, mw=4(p&1)+r ----
    // d = d0+zbase+2ddg+khp, h = h0+q, w = w0+8wh+4kb+r. Residual from LDS tile.
#pragma unroll
    for (int ddg = 0; ddg < 4; ddg++) {
#pragma unroll
        for (int wh = 0; wh < 2; wh++) {
            const int d = d0 + zbase + 2 * ddg + khp;
            const int Rr = (zbase + 2 * ddg + khp + 3) * HR + (q + 3);
            uint2 u = *(const uint2*)&tile[Rr * RCOLS + 8 * wh + 4 * kb + 4];
            float xr[4];
            xr[0] = __builtin_bit_cast(float, u.x << 16);
            xr[1] = __builtin_bit_cast(float, u.x & 0xffff0000u);
            xr[2] = __builtin_bit_cast(float, u.y << 16);
            xr[3] = __builtin_bit_cast(float, u.y & 0xffff0000u);

            size_t off = ((size_t)(nb * Cc + c) * Dd + d) * (Hh * Ww)
                       + (size_t)(h0 + q) * Ww + w0 + 8 * wh + 4 * kb;
            float o[4];
#pragma unroll
            for (int r = 0; r < 4; r++) {
                float y7 = fmaxf(fmaf(acc7[ddg][wh][r], iv7, bb7), 0.f);
                float y3 = fmaxf(fmaf(acc3[ddg][wh][r], iv3, bb3), 0.f);
                float y1 = fmaxf(fmaf(xr[r], s1, bb1), 0.f);
                o[r] = fmaxf(xr[r] + y7 + y3 + y1, 0.f);
            }
            *(float4*)(out + off) = make_float4(o[0], o[1], o[2], o[3]);
        }
    }
}

extern "C" void kernel_launch(void* const* d_in, const int* in_sizes, int n_in,
                              void* d_out, int out_size, void* d_ws, size_t ws_size,
                              hipStream_t stream) {
    const float* x  = (const float*)d_in[0];
    const float* w7 = (const float*)d_in[1];
    const float* w3 = (const float*)d_in[2];
    const float* w1 = (const float*)d_in[3];
    const float* g7 = (const float*)d_in[4];
    const float* b7 = (const float*)d_in[5];
    const float* m7 = (const float*)d_in[6];
    const float* v7 = (const float*)d_in[7];
    const float* g3 = (const float*)d_in[8];
    const float* b3 = (const float*)d_in[9];
    const float* m3 = (const float*)d_in[10];
    const float* v3 = (const float*)d_in[11];
    const float* g1 = (const float*)d_in[12];
    const float* b1 = (const float*)d_in[13];
    const float* m1 = (const float*)d_in[14];
    const float* v1 = (const float*)d_in[15];
    float* out = (float*)d_out;

    dim3 grid(8192);   // 1-D; kernel swizzles to (slab, tile) XCD-contiguously
    dim3 block(256);
    hipLaunchKernelGGL(replk_mfma, grid, block, 0, stream,
                       x, w7, w3, w1, g7, b7, m7, v7, g3, b3, m3, v3,
                       g1, b1, m1, v1, out);
}